// Round 4
// baseline (1421.882 us; speedup 1.0000x reference)
//
#include <hip/hip_runtime.h>

#define NN 16384   // n_nodes
#define DD 64      // feature dim

typedef _Float16 f16x8 __attribute__((ext_vector_type(8)));
typedef short    s16x8 __attribute__((ext_vector_type(8)));
typedef float    f32x4 __attribute__((ext_vector_type(4)));
typedef int      i32x4 __attribute__((ext_vector_type(4)));

// k-permutation within each 32-wide k-step: logical j of lane-group q maps to
// physical k = q*4 + (j&3) + (j>=4 ? 16 : 0).  This makes the A (adj) loads
// full-cache-line per vmem instruction (lanes q=0..3 cover one 64B line).
// B is written by prep_x in the SAME permuted order, so the MFMA dot product
// is unchanged (permutation-invariant).
__device__ __forceinline__ int kperm(int q, int j) {
    return q * 4 + (j & 3) + ((j >> 2) << 4);
}

// ---------------------------------------------------------------------------
// Pre-pass: x (fp32 [NN][64]) -> f16 in permuted MFMA B-fragment order:
//   ws[((t*4 + c)*64 + l)*8 + j] = x[32*t + kperm(l>>4, j)][c*16 + (l&15)]
// 2 MiB total -> L2-resident for the whole GEMM.
// ---------------------------------------------------------------------------
__global__ __launch_bounds__(256) void prep_x(const float* __restrict__ x,
                                              _Float16* __restrict__ ws) {
    int tid = blockIdx.x * 256 + threadIdx.x;   // (t*4+c)*64 + l ; 131072 total
    int l  = tid & 63;
    int tc = tid >> 6;
    int c  = tc & 3;
    int t  = tc >> 2;
    int q  = l >> 4;
    int m  = l & 15;
    int col = c * 16 + m;
    f16x8 v;
#pragma unroll
    for (int j = 0; j < 8; ++j) {
        int row = t * 32 + kperm(q, j);
        v[j] = (_Float16)x[(size_t)row * DD + col];
    }
    *(f16x8*)(ws + (size_t)tid * 8) = v;
}

// ---------------------------------------------------------------------------
// Main GEMM, barrier-free: one wave per block, 16 rows/wave, all 64 cols.
// Per 128-k chunk: A = 8 fully-line-coalesced nontemporal dwordx4 (each instr
// = 16 rows x one full 64B line), B = 16 f16x8 frags (L2-hot). Double-
// buffered; next chunk issued before consuming current -> vmcnt never drains.
// ---------------------------------------------------------------------------
__global__ __launch_bounds__(64, 2) void graphpool_gemm(const int* __restrict__ adj,
                                                        const float* __restrict__ x,
                                                        const _Float16* __restrict__ xs,
                                                        float* __restrict__ out) {
    const int l = threadIdx.x;   // 1 wave per block
    const int q = l >> 4;
    const int m = l & 15;
    const int row16 = blockIdx.x * 16;

    // A: lane (m,q), kstep s of chunk n: ints [n*128 + s*32 + q*4 .. +4) and
    // [n*128 + s*32 + 16 + q*4 .. +4) of row (row16+m)  -> two full-line instrs
    const int* aptr = adj + (size_t)(row16 + m) * NN + q * 4;
    // B: frag f of chunk n at xs + (n*1024 + f*64 + l)*8 f16 (16B contiguous)
    const f16x8* bbase = (const f16x8*)xs + l;

    f32x4 acc[4];
#pragma unroll
    for (int c = 0; c < 4; ++c) acc[c] = (f32x4){0.f, 0.f, 0.f, 0.f};

    i32x4 areg[2][4][2];   // [buf][kstep s][lo/hi half] = 8 adj ints per kstep
    f16x8 breg[2][16];     // [buf][frag]

    auto loadA = [&](int n, int buf) {
        const int* base = aptr + (size_t)n * 128;
#pragma unroll
        for (int s = 0; s < 4; ++s) {
            const i32x4* p0 = (const i32x4*)(base + s * 32);        // line 0
            const i32x4* p1 = (const i32x4*)(base + s * 32 + 16);   // line 1
            areg[buf][s][0] = __builtin_nontemporal_load(p0);
            areg[buf][s][1] = __builtin_nontemporal_load(p1);
        }
    };
    auto loadB = [&](int n, int buf) {
        const f16x8* src = bbase + (size_t)n * 1024;
#pragma unroll
        for (int f = 0; f < 16; ++f) breg[buf][f] = src[f * 64];
    };
    auto compute = [&](int buf) {
#pragma unroll
        for (int s = 0; s < 4; ++s) {
            int av[8];
            {
                i32x4 v0 = areg[buf][s][0], v1 = areg[buf][s][1];
                av[0] = v0.x; av[1] = v0.y; av[2] = v0.z; av[3] = v0.w;
                av[4] = v1.x; av[5] = v1.y; av[6] = v1.z; av[7] = v1.w;
            }
            s16x8 ai;
#pragma unroll
            for (int j = 0; j < 8; ++j)
                ai[j] = av[j] ? (short)0x3C00 : (short)0;   // 0/1 -> f16 1.0/0.0
            f16x8 af = __builtin_bit_cast(f16x8, ai);
#pragma unroll
            for (int c = 0; c < 4; ++c)
                acc[c] = __builtin_amdgcn_mfma_f32_16x16x32_f16(af, breg[buf][s * 4 + c],
                                                                acc[c], 0, 0, 0);
        }
    };

    // prologue: chunk 0 into buf 0
    loadB(0, 0);
    loadA(0, 0);

    for (int n = 0; n < NN / 128; n += 2) {
        if (n + 1 < NN / 128) { loadB(n + 1, 1); loadA(n + 1, 1); }
        compute(0);            // waits only on chunk-n loads (older than n+1's)
        if (n + 2 < NN / 128) { loadB(n + 2, 0); loadA(n + 2, 0); }
        compute(1);
    }

    // epilogue: C layout col=l&15, row=(l>>4)*4+r ; add self term +x
#pragma unroll
    for (int c = 0; c < 4; ++c) {
#pragma unroll
        for (int r = 0; r < 4; ++r) {
            int row = row16 + q * 4 + r;
            int col = c * 16 + m;
            size_t off = (size_t)row * DD + col;
            out[off] = acc[c][r] + x[off];
        }
    }
}

// ---------------------------------------------------------------------------
// Safety-net fallback if ws is too small for the swizzled x (2 MiB).
// ---------------------------------------------------------------------------
__global__ void graphpool_fallback(const int* __restrict__ adj,
                                   const float* __restrict__ x,
                                   float* __restrict__ out) {
    int i = blockIdx.x;
    int d = threadIdx.x;   // 64 threads
    float acc = x[(size_t)i * DD + d];
    const int* row = adj + (size_t)i * NN;
    for (int j = 0; j < NN; ++j)
        if (row[j]) acc += x[(size_t)j * DD + d];
    out[(size_t)i * DD + d] = acc;
}

extern "C" void kernel_launch(void* const* d_in, const int* in_sizes, int n_in,
                              void* d_out, int out_size, void* d_ws, size_t ws_size,
                              hipStream_t stream) {
    const float* x   = (const float*)d_in[0];
    const int*   adj = (const int*)d_in[1];
    float*       out = (float*)d_out;

    const size_t ws_needed = (size_t)NN * DD * sizeof(_Float16);   // 2 MiB
    if (ws_size >= ws_needed) {
        _Float16* xs = (_Float16*)d_ws;
        prep_x<<<512, 256, 0, stream>>>(x, xs);
        graphpool_gemm<<<NN / 16, 64, 0, stream>>>(adj, x, xs, out);
    } else {
        graphpool_fallback<<<NN, 64, 0, stream>>>(adj, x, out);
    }
}

// Round 5
// 1393.785 us; speedup vs baseline: 1.0202x; 1.0202x over previous
//
#include <hip/hip_runtime.h>

#define NN 16384   // n_nodes
#define DD 64      // feature dim

typedef _Float16 f16x8 __attribute__((ext_vector_type(8)));
typedef float    f32x4 __attribute__((ext_vector_type(4)));
typedef int      i32x4 __attribute__((ext_vector_type(4)));

// k-permutation within each 32-wide k-step: logical j of lane-group q maps to
// physical k = q*4 + (j&3) + (j>=4 ? 16 : 0).  A-load instr pair then covers
// bytes [0,64) and [64,128) of each row's kstep window: one full 128B L2
// granule per instr pair. prep_x writes B in the same permuted order, so the
// MFMA dot product is unchanged (k-permutation-invariant).
__device__ __forceinline__ int kperm(int q, int j) {
    return q * 4 + (j & 3) + ((j >> 2) << 4);
}

// ---------------------------------------------------------------------------
// Pre-pass: x (fp32 [NN][64]) -> f16 in permuted MFMA B-fragment order:
//   ws[((t*4 + c)*64 + l)*8 + j] = x[32*t + kperm(l>>4, j)][c*16 + (l&15)]
// 2 MiB total -> L2-resident for the whole GEMM.
// ---------------------------------------------------------------------------
__global__ __launch_bounds__(256) void prep_x(const float* __restrict__ x,
                                              _Float16* __restrict__ ws) {
    int tid = blockIdx.x * 256 + threadIdx.x;   // (t*4+c)*64 + l ; 131072 total
    int l  = tid & 63;
    int tc = tid >> 6;
    int c  = tc & 3;
    int t  = tc >> 2;
    int q  = l >> 4;
    int m  = l & 15;
    int col = c * 16 + m;
    f16x8 v;
#pragma unroll
    for (int j = 0; j < 8; ++j) {
        int row = t * 32 + kperm(q, j);
        v[j] = (_Float16)x[(size_t)row * DD + col];
    }
    *(f16x8*)(ws + (size_t)tid * 8) = v;
}

// ---------------------------------------------------------------------------
// Main GEMM, barrier-free: one wave per block, 16 rows/wave, all 64 cols.
// A (adj) = plain (cached!) dwordx4 pairs, each pair = one full 128B granule
// per row; B = 16 f16x8 frags (L2-hot). Double-buffered, next chunk issued
// before consuming current -> vmcnt pipeline stays full, no barriers.
// 0/1 -> packed-f16 repack via (lo | hi<<16) * 0x3C00 (2 VALU per dword pair).
// ---------------------------------------------------------------------------
__global__ __launch_bounds__(64, 2) void graphpool_gemm(const int* __restrict__ adj,
                                                        const float* __restrict__ x,
                                                        const _Float16* __restrict__ xs,
                                                        float* __restrict__ out) {
    const int l = threadIdx.x;   // 1 wave per block
    const int q = l >> 4;
    const int m = l & 15;
    const int row16 = blockIdx.x * 16;

    // A: lane (m,q), kstep s of chunk n: ints [n*128+s*32+q*4 ..+4) and
    // [n*128+s*32+16+q*4 ..+4) of row (row16+m)
    const int* aptr = adj + (size_t)(row16 + m) * NN + q * 4;
    // B: frag f of chunk n at xs + (n*1024 + f*64 + l)*8 f16 (16B contiguous)
    const f16x8* bbase = (const f16x8*)xs + l;

    f32x4 acc[4];
#pragma unroll
    for (int c = 0; c < 4; ++c) acc[c] = (f32x4){0.f, 0.f, 0.f, 0.f};

    i32x4 areg[2][4][2];   // [buf][kstep s][lo/hi half] = 8 adj ints per kstep
    f16x8 breg[2][16];     // [buf][frag]

    auto loadA = [&](int n, int buf) {
        const int* base = aptr + (size_t)n * 128;
#pragma unroll
        for (int s = 0; s < 4; ++s) {
            areg[buf][s][0] = *(const i32x4*)(base + s * 32);        // bytes [0,64)
            areg[buf][s][1] = *(const i32x4*)(base + s * 32 + 16);   // bytes [64,128)
        }
    };
    auto loadB = [&](int n, int buf) {
        const f16x8* src = bbase + (size_t)n * 1024;
#pragma unroll
        for (int f = 0; f < 16; ++f) breg[buf][f] = src[f * 64];
    };
    auto compute = [&](int buf) {
#pragma unroll
        for (int s = 0; s < 4; ++s) {
            i32x4 v0 = areg[buf][s][0], v1 = areg[buf][s][1];
            // adj entries are exactly 0/1: two packed f16 per dword pair.
            i32x4 p;
            p.x = (v0.x + (v0.y << 16)) * 0x3C00;
            p.y = (v0.z + (v0.w << 16)) * 0x3C00;
            p.z = (v1.x + (v1.y << 16)) * 0x3C00;
            p.w = (v1.z + (v1.w << 16)) * 0x3C00;
            f16x8 af = __builtin_bit_cast(f16x8, p);
#pragma unroll
            for (int c = 0; c < 4; ++c)
                acc[c] = __builtin_amdgcn_mfma_f32_16x16x32_f16(af, breg[buf][s * 4 + c],
                                                                acc[c], 0, 0, 0);
        }
    };

    // prologue: chunk 0 into buf 0
    loadB(0, 0);
    loadA(0, 0);

    for (int n = 0; n < NN / 128; n += 2) {
        if (n + 1 < NN / 128) { loadB(n + 1, 1); loadA(n + 1, 1); }
        compute(0);            // waits only on chunk-n loads (older than n+1's)
        if (n + 2 < NN / 128) { loadB(n + 2, 0); loadA(n + 2, 0); }
        compute(1);
    }

    // epilogue: C layout col=l&15, row=(l>>4)*4+r ; add self term +x
#pragma unroll
    for (int c = 0; c < 4; ++c) {
#pragma unroll
        for (int r = 0; r < 4; ++r) {
            int row = row16 + q * 4 + r;
            int col = c * 16 + m;
            size_t off = (size_t)row * DD + col;
            out[off] = acc[c][r] + x[off];
        }
    }
}

// ---------------------------------------------------------------------------
// Safety-net fallback if ws is too small for the swizzled x (2 MiB).
// ---------------------------------------------------------------------------
__global__ void graphpool_fallback(const int* __restrict__ adj,
                                   const float* __restrict__ x,
                                   float* __restrict__ out) {
    int i = blockIdx.x;
    int d = threadIdx.x;   // 64 threads
    float acc = x[(size_t)i * DD + d];
    const int* row = adj + (size_t)i * NN;
    for (int j = 0; j < NN; ++j)
        if (row[j]) acc += x[(size_t)j * DD + d];
    out[(size_t)i * DD + d] = acc;
}

extern "C" void kernel_launch(void* const* d_in, const int* in_sizes, int n_in,
                              void* d_out, int out_size, void* d_ws, size_t ws_size,
                              hipStream_t stream) {
    const float* x   = (const float*)d_in[0];
    const int*   adj = (const int*)d_in[1];
    float*       out = (float*)d_out;

    const size_t ws_needed = (size_t)NN * DD * sizeof(_Float16);   // 2 MiB
    if (ws_size >= ws_needed) {
        _Float16* xs = (_Float16*)d_ws;
        prep_x<<<512, 256, 0, stream>>>(x, xs);
        graphpool_gemm<<<NN / 16, 64, 0, stream>>>(adj, x, xs, out);
    } else {
        graphpool_fallback<<<NN, 64, 0, stream>>>(adj, x, out);
    }
}